// Round 1
// baseline (244.857 us; speedup 1.0000x reference)
//
#include <hip/hip_runtime.h>

#define NB   32
#define DIMK 512
#define MM   32
#define ZZ   64
#define MZV  2048
#define VOC  50257

// ws layout in floats
#define WS_W      0                       // [NB][MZV] raw scores (incl. log mask)
#define WS_PVEC   (WS_W + NB*MZV)         // [NB][MM][DIMK] partial weighted vecs
#define WS_LSTAT  (WS_PVEC + NB*MM*DIMK)  // [NB][MM][2] (max, sum)
#define WS_GSTATW (WS_LSTAT + NB*MM*2)    // [NB][2] global (max,sum) copy branch
#define WS_MIX    (WS_GSTATW + NB*2)      // [NB][2]
#define WS_GPART  (WS_MIX + NB*2)         // [NB][32][2] gen softmax partials
#define WS_GSTATG (WS_GPART + NB*32*2)    // [NB][2]

// K1: per (b,m) block — scores + online-softmax weighted sum, memencs read ONCE
__global__ __launch_bounds__(256) void k1_mem(
    const float* __restrict__ enc, const float* __restrict__ embsumm,
    const float* __restrict__ memencs, const float* __restrict__ memembsumm,
    const float* __restrict__ memmask, float* __restrict__ ws)
{
    int blk = blockIdx.x;
    int b = blk >> 5, m = blk & 31;
    int tid = threadIdx.x, wid = tid >> 6, lane = tid & 63;
    int c0 = lane * 4, c1 = c0 + 256;
    const float* encb = enc + b * DIMK;
    const float* embb = embsumm + b * DIMK;
    float4 qe0 = *(const float4*)(encb + c0);
    float4 qe1 = *(const float4*)(encb + c1);
    float4 qm0 = *(const float4*)(embb + c0);
    float4 qm1 = *(const float4*)(embb + c1);
    const float* meb = memencs    + (long)(b*MM + m) * ZZ * DIMK;
    const float* mmb = memembsumm + (long)(b*MM + m) * ZZ * DIMK;
    const float* mkb = memmask    + (long)(b*MM + m) * ZZ;
    float* w_ws = ws + WS_W + b*MZV + m*ZZ;

    float lmax = -3.0e38f, lsum = 0.f;
    float4 a0 = make_float4(0.f,0.f,0.f,0.f), a1 = make_float4(0.f,0.f,0.f,0.f);

    for (int z = wid; z < ZZ; z += 4) {
        const float* mer = meb + z*DIMK;
        const float* mmr = mmb + z*DIMK;
        float4 e0 = *(const float4*)(mer + c0);
        float4 e1 = *(const float4*)(mer + c1);
        float4 s0 = *(const float4*)(mmr + c0);
        float4 s1 = *(const float4*)(mmr + c1);
        float d = e0.x*qe0.x + e0.y*qe0.y + e0.z*qe0.z + e0.w*qe0.w
                + e1.x*qe1.x + e1.y*qe1.y + e1.z*qe1.z + e1.w*qe1.w
                + s0.x*qm0.x + s0.y*qm0.y + s0.z*qm0.z + s0.w*qm0.w
                + s1.x*qm1.x + s1.y*qm1.y + s1.z*qm1.z + s1.w*qm1.w;
        #pragma unroll
        for (int off = 32; off; off >>= 1) d += __shfl_xor(d, off);
        d += logf(mkb[z]);                 // mask=1 -> +0; mask=0 -> -inf
        if (lane == 0) w_ws[z] = d;
        // online softmax update; acc dims = exactly the loaded memencs cols
        float nm = fmaxf(lmax, d);
        float sc = __expf(lmax - nm);
        float e  = __expf(d - nm);
        lsum = lsum * sc + e;
        a0.x = a0.x*sc + e*e0.x; a0.y = a0.y*sc + e*e0.y;
        a0.z = a0.z*sc + e*e0.z; a0.w = a0.w*sc + e*e0.w;
        a1.x = a1.x*sc + e*e1.x; a1.y = a1.y*sc + e*e1.y;
        a1.z = a1.z*sc + e*e1.z; a1.w = a1.w*sc + e*e1.w;
        lmax = nm;
    }

    __shared__ float sacc[4][DIMK];
    __shared__ float sst[4][2];
    *(float4*)&sacc[wid][c0] = a0;
    *(float4*)&sacc[wid][c1] = a1;
    if (lane == 0) { sst[wid][0] = lmax; sst[wid][1] = lsum; }
    __syncthreads();
    float bm = fmaxf(fmaxf(sst[0][0], sst[1][0]), fmaxf(sst[2][0], sst[3][0]));
    float sc0 = __expf(sst[0][0]-bm), sc1 = __expf(sst[1][0]-bm);
    float sc2 = __expf(sst[2][0]-bm), sc3 = __expf(sst[3][0]-bm);
    float bs = sst[0][1]*sc0 + sst[1][1]*sc1 + sst[2][1]*sc2 + sst[3][1]*sc3;
    int d0 = tid * 2;
    float2 v0 = *(float2*)&sacc[0][d0];
    float2 v1 = *(float2*)&sacc[1][d0];
    float2 v2 = *(float2*)&sacc[2][d0];
    float2 v3 = *(float2*)&sacc[3][d0];
    float p0 = v0.x*sc0 + v1.x*sc1 + v2.x*sc2 + v3.x*sc3;
    float p1 = v0.y*sc0 + v1.y*sc1 + v2.y*sc2 + v3.y*sc3;
    float* pv = ws + WS_PVEC + (long)(b*MM+m)*DIMK + d0;
    pv[0] = p0; pv[1] = p1;
    if (tid == 0) { float* ls = ws + WS_LSTAT + (b*MM+m)*2; ls[0] = bm; ls[1] = bs; }
}

// K2: combine the 32 m-partials per b -> mem_enc_summ (output 1) + global (max,sum)
__global__ __launch_bounds__(256) void k2_comb(float* __restrict__ out, float* __restrict__ ws)
{
    int b = blockIdx.x, tid = threadIdx.x;
    const float* ls = ws + WS_LSTAT + b*MM*2;
    float gm = -3.0e38f;
    #pragma unroll
    for (int m = 0; m < MM; m++) gm = fmaxf(gm, ls[m*2]);
    float gs = 0.f;
    #pragma unroll
    for (int m = 0; m < MM; m++) gs += ls[m*2+1] * __expf(ls[m*2] - gm);
    if (tid == 0) { ws[WS_GSTATW + b*2] = gm; ws[WS_GSTATW + b*2 + 1] = gs; }
    float inv = 1.0f / gs;
    int d0 = tid * 2;
    float p0 = 0.f, p1 = 0.f;
    for (int m = 0; m < MM; m++) {
        float sc = __expf(ls[m*2] - gm);
        const float* pv = ws + WS_PVEC + (long)(b*MM+m)*DIMK + d0;
        p0 += pv[0]*sc; p1 += pv[1]*sc;
    }
    out[(long)NB*VOC + b*DIMK + d0]     = p0 * inv;
    out[(long)NB*VOC + b*DIMK + d0 + 1] = p1 * inv;
}

// K3: mixer gates
__global__ void k3_mix(const float* __restrict__ encsumm, const float* __restrict__ enc,
                       const float* __restrict__ W_mix, const float* __restrict__ b_mix,
                       float* __restrict__ ws)
{
    int b = blockIdx.x, l = threadIdx.x;
    float d0 = 0.f, d1 = 0.f;
    #pragma unroll
    for (int p = 0; p < 4; p++) {
        int cc = l*4 + p*256;
        float4 h4 = (cc < 512) ? *(const float4*)(encsumm + b*DIMK + cc)
                               : *(const float4*)(enc + b*DIMK + cc - 512);
        float4 w0 = *(const float4*)(W_mix + cc);
        float4 w1 = *(const float4*)(W_mix + 1024 + cc);
        d0 += h4.x*w0.x + h4.y*w0.y + h4.z*w0.z + h4.w*w0.w;
        d1 += h4.x*w1.x + h4.y*w1.y + h4.z*w1.z + h4.w*w1.w;
    }
    #pragma unroll
    for (int off = 32; off; off >>= 1) { d0 += __shfl_xor(d0, off); d1 += __shfl_xor(d1, off); }
    if (l == 0) {
        d0 += b_mix[0]; d1 += b_mix[1];
        float mx = fmaxf(d0, d1);
        float e0 = __expf(d0-mx), e1 = __expf(d1-mx);
        float s = e0 + e1;
        ws[WS_MIX + b*2] = e0/s; ws[WS_MIX + b*2 + 1] = e1/s;
    }
}

// K4: gen logits = h @ W_out^T + b_out + log(unk). Wave owns one v for 8 batch rows;
// h in registers; bisection-pack cross-lane reduce. Writes logits into d_out probs region.
__global__ __launch_bounds__(256) void k4_gemm(
    const float* __restrict__ encsumm, const float* __restrict__ enc,
    const float* __restrict__ W_out, const float* __restrict__ b_out,
    const float* __restrict__ unk, float* __restrict__ logits)
{
    int tid = threadIdx.x, wid = tid >> 6, lane = tid & 63;
    int c = lane * 4;
    float4 h[8][4];
    #pragma unroll
    for (int i = 0; i < 8; i++) {
        int b = wid*8 + i;
        h[i][0] = *(const float4*)(encsumm + b*DIMK + c);
        h[i][1] = *(const float4*)(encsumm + b*DIMK + c + 256);
        h[i][2] = *(const float4*)(enc + b*DIMK + c);
        h[i][3] = *(const float4*)(enc + b*DIMK + c + 256);
    }
    for (int v = blockIdx.x; v < VOC; v += gridDim.x) {
        const float* wr = W_out + (long)v * 1024;
        float a[8] = {0.f,0.f,0.f,0.f,0.f,0.f,0.f,0.f};
        #pragma unroll
        for (int p = 0; p < 4; p++) {
            float4 wq = *(const float4*)(wr + c + p*256);
            #pragma unroll
            for (int i = 0; i < 8; i++)
                a[i] += wq.x*h[i][p].x + wq.y*h[i][p].y + wq.z*h[i][p].z + wq.w*h[i][p].w;
        }
        bool b5 = (lane & 32) != 0;
        float k0 = b5?a[4]:a[0], s0 = b5?a[0]:a[4];
        float k1 = b5?a[5]:a[1], s1 = b5?a[1]:a[5];
        float k2 = b5?a[6]:a[2], s2 = b5?a[2]:a[6];
        float k3 = b5?a[7]:a[3], s3 = b5?a[3]:a[7];
        k0 += __shfl_xor(s0, 32); k1 += __shfl_xor(s1, 32);
        k2 += __shfl_xor(s2, 32); k3 += __shfl_xor(s3, 32);
        bool b4 = (lane & 16) != 0;
        float m0 = b4?k2:k0, n0 = b4?k0:k2;
        float m1 = b4?k3:k1, n1 = b4?k1:k3;
        m0 += __shfl_xor(n0, 16); m1 += __shfl_xor(n1, 16);
        bool b3 = (lane & 8) != 0;
        float r = b3?m1:m0, q = b3?m0:m1;
        r += __shfl_xor(q, 8);
        r += __shfl_xor(r, 4);
        r += __shfl_xor(r, 2);
        r += __shfl_xor(r, 1);
        float bias = b_out[v] + logf(unk[v]);
        float logit = r + bias;
        if ((lane & 7) == 0) {
            int b = wid*8 + ((lane >> 3) & 7);
            logits[(long)b*VOC + v] = logit;
        }
    }
}

// K5: gen softmax stats, 32 chunks per b
__global__ __launch_bounds__(256) void k5_gstat(const float* __restrict__ logits, float* __restrict__ ws)
{
    int chunk = blockIdx.x, b = blockIdx.y, tid = threadIdx.x;
    const int CH = (VOC + 31) / 32;
    int v0 = chunk * CH;
    int v1 = min(VOC, v0 + CH);
    float m = -3.0e38f, s = 0.f;
    for (int v = v0 + tid; v < v1; v += 256) {
        float x = logits[(long)b*VOC + v];
        float nm = fmaxf(m, x);
        s = s*__expf(m - nm) + __expf(x - nm);
        m = nm;
    }
    #pragma unroll
    for (int off = 32; off; off >>= 1) {
        float om = __shfl_xor(m, off), os = __shfl_xor(s, off);
        float nm = fmaxf(m, om);
        s = s*__expf(m - nm) + os*__expf(om - nm);
        m = nm;
    }
    __shared__ float sm[4], ssum[4];
    int wid = tid >> 6, lane = tid & 63;
    if (lane == 0) { sm[wid] = m; ssum[wid] = s; }
    __syncthreads();
    if (tid == 0) {
        float gm = fmaxf(fmaxf(sm[0], sm[1]), fmaxf(sm[2], sm[3]));
        float gs = ssum[0]*__expf(sm[0]-gm) + ssum[1]*__expf(sm[1]-gm)
                 + ssum[2]*__expf(sm[2]-gm) + ssum[3]*__expf(sm[3]-gm);
        ws[WS_GPART + (b*32 + chunk)*2]     = gm;
        ws[WS_GPART + (b*32 + chunk)*2 + 1] = gs;
    }
}

// K5b: merge 32 chunk partials per b
__global__ void k5b_merge(float* __restrict__ ws)
{
    int b = blockIdx.x, l = threadIdx.x;
    float m = -3.0e38f, s = 0.f;
    if (l < 32) { m = ws[WS_GPART + (b*32+l)*2]; s = ws[WS_GPART + (b*32+l)*2 + 1]; }
    #pragma unroll
    for (int off = 32; off; off >>= 1) {
        float om = __shfl_xor(m, off), os = __shfl_xor(s, off);
        float nm = fmaxf(m, om);
        s = s*__expf(m - nm) + os*__expf(om - nm);
        m = nm;
    }
    if (l == 0) { ws[WS_GSTATG + b*2] = m; ws[WS_GSTATG + b*2 + 1] = s; }
}

// K6: probs = mix0 * softmax(logits), in place in d_out
__global__ __launch_bounds__(256) void k6_final(float* __restrict__ probs, const float* __restrict__ ws)
{
    int v = blockIdx.x*256 + threadIdx.x;
    int b = blockIdx.y;
    if (v >= VOC) return;
    float gm = ws[WS_GSTATG + b*2], gs = ws[WS_GSTATG + b*2 + 1];
    float mix0 = ws[WS_MIX + b*2];
    long idx = (long)b*VOC + v;
    probs[idx] = mix0 * __expf(probs[idx] - gm) / gs;
}

// K7: copy-branch scatter: probs[b, tok] += mix1*alpha
__global__ __launch_bounds__(256) void k7_scatter(const int* __restrict__ memids,
                                                  const float* __restrict__ ws,
                                                  float* __restrict__ probs)
{
    int idx = blockIdx.x*256 + threadIdx.x;   // NB*MZV = 65536
    int b = idx >> 11, mz = idx & 2047;
    float gm = ws[WS_GSTATW + b*2], gs = ws[WS_GSTATW + b*2 + 1];
    float mix1 = ws[WS_MIX + b*2 + 1];
    float alpha = __expf(ws[WS_W + b*MZV + mz] - gm) / gs;
    int tok = memids[b*MZV + mz];
    atomicAdd(&probs[(long)b*VOC + tok], mix1 * alpha);
}

extern "C" void kernel_launch(void* const* d_in, const int* in_sizes, int n_in,
                              void* d_out, int out_size, void* d_ws, size_t ws_size,
                              hipStream_t stream)
{
    const float* enc        = (const float*)d_in[0];
    const float* encsumm    = (const float*)d_in[1];
    const float* embsumm    = (const float*)d_in[2];
    const float* memencs    = (const float*)d_in[3];
    // d_in[4] = memencsumm: provably unused (zeros in both concat middles)
    const float* memembsumm = (const float*)d_in[5];
    const float* memmask    = (const float*)d_in[6];
    const int*   memids     = (const int*)d_in[7];
    const float* W_out      = (const float*)d_in[8];
    const float* b_out      = (const float*)d_in[9];
    const float* W_mix      = (const float*)d_in[10];
    const float* b_mix      = (const float*)d_in[11];
    const float* unk        = (const float*)d_in[12];
    float* out = (float*)d_out;
    float* ws  = (float*)d_ws;

    hipLaunchKernelGGL(k1_mem, dim3(NB*MM), dim3(256), 0, stream,
                       enc, embsumm, memencs, memembsumm, memmask, ws);
    hipLaunchKernelGGL(k2_comb, dim3(NB), dim3(256), 0, stream, out, ws);
    hipLaunchKernelGGL(k3_mix, dim3(NB), dim3(64), 0, stream, encsumm, enc, W_mix, b_mix, ws);
    hipLaunchKernelGGL(k4_gemm, dim3(1024), dim3(256), 0, stream,
                       encsumm, enc, W_out, b_out, unk, out);
    hipLaunchKernelGGL(k5_gstat, dim3(32, NB), dim3(256), 0, stream, out, ws);
    hipLaunchKernelGGL(k5b_merge, dim3(NB), dim3(64), 0, stream, ws);
    hipLaunchKernelGGL(k6_final, dim3((VOC + 255)/256, NB), dim3(256), 0, stream, out, ws);
    hipLaunchKernelGGL(k7_scatter, dim3(NB*MZV/256), dim3(256), 0, stream, memids, ws, out);
}

// Round 2
// 232.301 us; speedup vs baseline: 1.0540x; 1.0540x over previous
//
#include <hip/hip_runtime.h>

#define NB   32
#define DIMK 512
#define MM   32
#define ZZ   64
#define MZV  2048
#define VOC  50257

// ws layout in floats
#define WS_W      0                       // [NB][MZV] raw scores (incl. log mask)
#define WS_PVEC   (WS_W + NB*MZV)         // [NB][MM][DIMK] partial weighted vecs
#define WS_LSTAT  (WS_PVEC + NB*MM*DIMK)  // [NB][MM][2] (max, sum)
#define WS_GSTATW (WS_LSTAT + NB*MM*2)    // [NB][2] global (max,sum) copy branch
#define WS_MIX    (WS_GSTATW + NB*2)      // [NB][2]
#define WS_GPART  (WS_MIX + NB*2)         // [NB][32][2] gen softmax partials
#define WS_GSTATG (WS_GPART + NB*32*2)    // [NB][2]
#define WS_H      (WS_GSTATG + NB*2)      // [NB][1024] h = concat(encsumm, enc)

// K0: stage h = concat(encsumm, enc) contiguous for k4's uniform loads
__global__ void k0_stageh(const float* __restrict__ encsumm, const float* __restrict__ enc,
                          float* __restrict__ ws)
{
    int b = blockIdx.x;
    int c = threadIdx.x * 4;                       // 0..1020
    const float* src = (c < DIMK) ? (encsumm + b*DIMK + c) : (enc + b*DIMK + (c - DIMK));
    *(float4*)(ws + WS_H + b*1024 + c) = *(const float4*)src;
}

// K1: per (b,m) block — scores + online-softmax weighted sum, memencs read ONCE
__global__ __launch_bounds__(256) void k1_mem(
    const float* __restrict__ enc, const float* __restrict__ embsumm,
    const float* __restrict__ memencs, const float* __restrict__ memembsumm,
    const float* __restrict__ memmask, float* __restrict__ ws)
{
    int blk = blockIdx.x;
    int b = blk >> 5, m = blk & 31;
    int tid = threadIdx.x, wid = tid >> 6, lane = tid & 63;
    int c0 = lane * 4, c1 = c0 + 256;
    const float* encb = enc + b * DIMK;
    const float* embb = embsumm + b * DIMK;
    float4 qe0 = *(const float4*)(encb + c0);
    float4 qe1 = *(const float4*)(encb + c1);
    float4 qm0 = *(const float4*)(embb + c0);
    float4 qm1 = *(const float4*)(embb + c1);
    const float* meb = memencs    + (long)(b*MM + m) * ZZ * DIMK;
    const float* mmb = memembsumm + (long)(b*MM + m) * ZZ * DIMK;
    const float* mkb = memmask    + (long)(b*MM + m) * ZZ;
    float* w_ws = ws + WS_W + b*MZV + m*ZZ;

    float lmax = -3.0e38f, lsum = 0.f;
    float4 a0 = make_float4(0.f,0.f,0.f,0.f), a1 = make_float4(0.f,0.f,0.f,0.f);

    for (int z = wid; z < ZZ; z += 4) {
        const float* mer = meb + z*DIMK;
        const float* mmr = mmb + z*DIMK;
        float4 e0 = *(const float4*)(mer + c0);
        float4 e1 = *(const float4*)(mer + c1);
        float4 s0 = *(const float4*)(mmr + c0);
        float4 s1 = *(const float4*)(mmr + c1);
        float d = e0.x*qe0.x + e0.y*qe0.y + e0.z*qe0.z + e0.w*qe0.w
                + e1.x*qe1.x + e1.y*qe1.y + e1.z*qe1.z + e1.w*qe1.w
                + s0.x*qm0.x + s0.y*qm0.y + s0.z*qm0.z + s0.w*qm0.w
                + s1.x*qm1.x + s1.y*qm1.y + s1.z*qm1.z + s1.w*qm1.w;
        #pragma unroll
        for (int off = 32; off; off >>= 1) d += __shfl_xor(d, off);
        d += logf(mkb[z]);                 // mask=1 -> +0; mask=0 -> -inf
        if (lane == 0) w_ws[z] = d;
        float nm = fmaxf(lmax, d);
        float sc = __expf(lmax - nm);
        float e  = __expf(d - nm);
        lsum = lsum * sc + e;
        a0.x = a0.x*sc + e*e0.x; a0.y = a0.y*sc + e*e0.y;
        a0.z = a0.z*sc + e*e0.z; a0.w = a0.w*sc + e*e0.w;
        a1.x = a1.x*sc + e*e1.x; a1.y = a1.y*sc + e*e1.y;
        a1.z = a1.z*sc + e*e1.z; a1.w = a1.w*sc + e*e1.w;
        lmax = nm;
    }

    __shared__ float sacc[4][DIMK];
    __shared__ float sst[4][2];
    *(float4*)&sacc[wid][c0] = a0;
    *(float4*)&sacc[wid][c1] = a1;
    if (lane == 0) { sst[wid][0] = lmax; sst[wid][1] = lsum; }
    __syncthreads();
    float bm = fmaxf(fmaxf(sst[0][0], sst[1][0]), fmaxf(sst[2][0], sst[3][0]));
    float sc0 = __expf(sst[0][0]-bm), sc1 = __expf(sst[1][0]-bm);
    float sc2 = __expf(sst[2][0]-bm), sc3 = __expf(sst[3][0]-bm);
    float bs = sst[0][1]*sc0 + sst[1][1]*sc1 + sst[2][1]*sc2 + sst[3][1]*sc3;
    int d0 = tid * 2;
    float2 v0 = *(float2*)&sacc[0][d0];
    float2 v1 = *(float2*)&sacc[1][d0];
    float2 v2 = *(float2*)&sacc[2][d0];
    float2 v3 = *(float2*)&sacc[3][d0];
    float p0 = v0.x*sc0 + v1.x*sc1 + v2.x*sc2 + v3.x*sc3;
    float p1 = v0.y*sc0 + v1.y*sc1 + v2.y*sc2 + v3.y*sc3;
    float* pv = ws + WS_PVEC + (long)(b*MM+m)*DIMK + d0;
    pv[0] = p0; pv[1] = p1;
    if (tid == 0) { float* ls = ws + WS_LSTAT + (b*MM+m)*2; ls[0] = bm; ls[1] = bs; }
}

// K2: combine the 32 m-partials per b -> mem_enc_summ (output 1) + global (max,sum)
__global__ __launch_bounds__(256) void k2_comb(float* __restrict__ out, float* __restrict__ ws)
{
    int b = blockIdx.x, tid = threadIdx.x;
    const float* ls = ws + WS_LSTAT + b*MM*2;
    float gm = -3.0e38f;
    #pragma unroll
    for (int m = 0; m < MM; m++) gm = fmaxf(gm, ls[m*2]);
    float gs = 0.f;
    #pragma unroll
    for (int m = 0; m < MM; m++) gs += ls[m*2+1] * __expf(ls[m*2] - gm);
    if (tid == 0) { ws[WS_GSTATW + b*2] = gm; ws[WS_GSTATW + b*2 + 1] = gs; }
    float inv = 1.0f / gs;
    int d0 = tid * 2;
    float p0 = 0.f, p1 = 0.f;
    for (int m = 0; m < MM; m++) {
        float sc = __expf(ls[m*2] - gm);
        const float* pv = ws + WS_PVEC + (long)(b*MM+m)*DIMK + d0;
        p0 += pv[0]*sc; p1 += pv[1]*sc;
    }
    out[(long)NB*VOC + b*DIMK + d0]     = p0 * inv;
    out[(long)NB*VOC + b*DIMK + d0 + 1] = p1 * inv;
}

// K3: mixer gates
__global__ void k3_mix(const float* __restrict__ encsumm, const float* __restrict__ enc,
                       const float* __restrict__ W_mix, const float* __restrict__ b_mix,
                       float* __restrict__ ws)
{
    int b = blockIdx.x, l = threadIdx.x;
    float d0 = 0.f, d1 = 0.f;
    #pragma unroll
    for (int p = 0; p < 4; p++) {
        int cc = l*4 + p*256;
        float4 h4 = (cc < 512) ? *(const float4*)(encsumm + b*DIMK + cc)
                               : *(const float4*)(enc + b*DIMK + cc - 512);
        float4 w0 = *(const float4*)(W_mix + cc);
        float4 w1 = *(const float4*)(W_mix + 1024 + cc);
        d0 += h4.x*w0.x + h4.y*w0.y + h4.z*w0.z + h4.w*w0.w;
        d1 += h4.x*w1.x + h4.y*w1.y + h4.z*w1.z + h4.w*w1.w;
    }
    #pragma unroll
    for (int off = 32; off; off >>= 1) { d0 += __shfl_xor(d0, off); d1 += __shfl_xor(d1, off); }
    if (l == 0) {
        d0 += b_mix[0]; d1 += b_mix[1];
        float mx = fmaxf(d0, d1);
        float e0 = __expf(d0-mx), e1 = __expf(d1-mx);
        float s = e0 + e1;
        ws[WS_MIX + b*2] = e0/s; ws[WS_MIX + b*2 + 1] = e1/s;
    }
}

// K4 v2: lane owns one vocab row v; streams W_out down K (float4, own row);
// h read as wave-uniform broadcast (readfirstlane base -> s_load from L2).
// 4 waves/block share the same 64 W rows (L1 reuse), cover 4 b-octets.
// No cross-lane reduce, no big per-lane arrays -> no spill.
__global__ __launch_bounds__(256) void k4_gemm(
    const float* __restrict__ hws,
    const float* __restrict__ W_out, const float* __restrict__ b_out,
    const float* __restrict__ unk, float* __restrict__ logits)
{
    int tid = threadIdx.x, wid = tid >> 6, lane = tid & 63;
    int v = blockIdx.x * 64 + lane;
    int vc = min(v, VOC - 1);
    const float* wr = W_out + (long)vc * 1024;
    int b0 = __builtin_amdgcn_readfirstlane(wid * 8);
    const float* hb = hws + b0 * 1024;

    float acc[8] = {0.f,0.f,0.f,0.f,0.f,0.f,0.f,0.f};
    for (int k = 0; k < 1024; k += 8) {
        float4 w0 = *(const float4*)(wr + k);
        float4 w1 = *(const float4*)(wr + k + 4);
        #pragma unroll
        for (int i = 0; i < 8; i++) {
            const float* hr = hb + i*1024 + k;
            float4 h0 = *(const float4*)(hr);
            float4 h1 = *(const float4*)(hr + 4);
            acc[i] += w0.x*h0.x + w0.y*h0.y + w0.z*h0.z + w0.w*h0.w
                    + w1.x*h1.x + w1.y*h1.y + w1.z*h1.z + w1.w*h1.w;
        }
    }
    if (v < VOC) {
        float bias = b_out[v] + logf(unk[v]);
        #pragma unroll
        for (int i = 0; i < 8; i++)
            logits[(long)(b0 + i)*VOC + v] = acc[i] + bias;
    }
}

// K5: gen softmax stats, 32 chunks per b
__global__ __launch_bounds__(256) void k5_gstat(const float* __restrict__ logits, float* __restrict__ ws)
{
    int chunk = blockIdx.x, b = blockIdx.y, tid = threadIdx.x;
    const int CH = (VOC + 31) / 32;
    int v0 = chunk * CH;
    int v1 = min(VOC, v0 + CH);
    float m = -3.0e38f, s = 0.f;
    for (int v = v0 + tid; v < v1; v += 256) {
        float x = logits[(long)b*VOC + v];
        float nm = fmaxf(m, x);
        s = s*__expf(m - nm) + __expf(x - nm);
        m = nm;
    }
    #pragma unroll
    for (int off = 32; off; off >>= 1) {
        float om = __shfl_xor(m, off), os = __shfl_xor(s, off);
        float nm = fmaxf(m, om);
        s = s*__expf(m - nm) + os*__expf(om - nm);
        m = nm;
    }
    __shared__ float sm[4], ssum[4];
    int wid = tid >> 6, lane = tid & 63;
    if (lane == 0) { sm[wid] = m; ssum[wid] = s; }
    __syncthreads();
    if (tid == 0) {
        float gm = fmaxf(fmaxf(sm[0], sm[1]), fmaxf(sm[2], sm[3]));
        float gs = ssum[0]*__expf(sm[0]-gm) + ssum[1]*__expf(sm[1]-gm)
                 + ssum[2]*__expf(sm[2]-gm) + ssum[3]*__expf(sm[3]-gm);
        ws[WS_GPART + (b*32 + chunk)*2]     = gm;
        ws[WS_GPART + (b*32 + chunk)*2 + 1] = gs;
    }
}

// K5b: merge 32 chunk partials per b
__global__ void k5b_merge(float* __restrict__ ws)
{
    int b = blockIdx.x, l = threadIdx.x;
    float m = -3.0e38f, s = 0.f;
    if (l < 32) { m = ws[WS_GPART + (b*32+l)*2]; s = ws[WS_GPART + (b*32+l)*2 + 1]; }
    #pragma unroll
    for (int off = 32; off; off >>= 1) {
        float om = __shfl_xor(m, off), os = __shfl_xor(s, off);
        float nm = fmaxf(m, om);
        s = s*__expf(m - nm) + os*__expf(om - nm);
        m = nm;
    }
    if (l == 0) { ws[WS_GSTATG + b*2] = m; ws[WS_GSTATG + b*2 + 1] = s; }
}

// K6: probs = mix0 * softmax(logits), in place in d_out
__global__ __launch_bounds__(256) void k6_final(float* __restrict__ probs, const float* __restrict__ ws)
{
    int v = blockIdx.x*256 + threadIdx.x;
    int b = blockIdx.y;
    if (v >= VOC) return;
    float gm = ws[WS_GSTATG + b*2], gs = ws[WS_GSTATG + b*2 + 1];
    float mix0 = ws[WS_MIX + b*2];
    long idx = (long)b*VOC + v;
    probs[idx] = mix0 * __expf(probs[idx] - gm) / gs;
}

// K7: copy-branch scatter: probs[b, tok] += mix1*alpha
__global__ __launch_bounds__(256) void k7_scatter(const int* __restrict__ memids,
                                                  const float* __restrict__ ws,
                                                  float* __restrict__ probs)
{
    int idx = blockIdx.x*256 + threadIdx.x;   // NB*MZV = 65536
    int b = idx >> 11, mz = idx & 2047;
    float gm = ws[WS_GSTATW + b*2], gs = ws[WS_GSTATW + b*2 + 1];
    float mix1 = ws[WS_MIX + b*2 + 1];
    float alpha = __expf(ws[WS_W + b*MZV + mz] - gm) / gs;
    int tok = memids[b*MZV + mz];
    atomicAdd(&probs[(long)b*VOC + tok], mix1 * alpha);
}

extern "C" void kernel_launch(void* const* d_in, const int* in_sizes, int n_in,
                              void* d_out, int out_size, void* d_ws, size_t ws_size,
                              hipStream_t stream)
{
    const float* enc        = (const float*)d_in[0];
    const float* encsumm    = (const float*)d_in[1];
    const float* embsumm    = (const float*)d_in[2];
    const float* memencs    = (const float*)d_in[3];
    // d_in[4] = memencsumm: provably unused (zeros in both concat middles)
    const float* memembsumm = (const float*)d_in[5];
    const float* memmask    = (const float*)d_in[6];
    const int*   memids     = (const int*)d_in[7];
    const float* W_out      = (const float*)d_in[8];
    const float* b_out      = (const float*)d_in[9];
    const float* W_mix      = (const float*)d_in[10];
    const float* b_mix      = (const float*)d_in[11];
    const float* unk        = (const float*)d_in[12];
    float* out = (float*)d_out;
    float* ws  = (float*)d_ws;

    hipLaunchKernelGGL(k0_stageh, dim3(NB), dim3(256), 0, stream, encsumm, enc, ws);
    hipLaunchKernelGGL(k1_mem, dim3(NB*MM), dim3(256), 0, stream,
                       enc, embsumm, memencs, memembsumm, memmask, ws);
    hipLaunchKernelGGL(k2_comb, dim3(NB), dim3(256), 0, stream, out, ws);
    hipLaunchKernelGGL(k3_mix, dim3(NB), dim3(64), 0, stream, encsumm, enc, W_mix, b_mix, ws);
    hipLaunchKernelGGL(k4_gemm, dim3((VOC + 63)/64), dim3(256), 0, stream,
                       ws + WS_H, W_out, b_out, unk, out);
    hipLaunchKernelGGL(k5_gstat, dim3(32, NB), dim3(256), 0, stream, out, ws);
    hipLaunchKernelGGL(k5b_merge, dim3(NB), dim3(64), 0, stream, ws);
    hipLaunchKernelGGL(k6_final, dim3((VOC + 255)/256, NB), dim3(256), 0, stream, out, ws);
    hipLaunchKernelGGL(k7_scatter, dim3(NB*MZV/256), dim3(256), 0, stream, memids, ws, out);
}